// Round 16
// baseline (130.042 us; speedup 1.0000x reference)
//
#include <hip/hip_runtime.h>
#include <math.h>

#define B_DIM 32
#define T_DIM 2048
#define D_DIM 512
#define V_DIM 5
#define L_DIM 256
#define LN2D 0.6931471805599453
#define TP (T_DIM + 4)

typedef const float __attribute__((address_space(1)))* gas_fp;
typedef float __attribute__((address_space(3)))* las_fp;

// ---- DPP helpers (VALU cross-lane, no DS pipe) ----
__device__ __forceinline__ float dpp_shr1_f32(float x) {
    return __int_as_float(__builtin_amdgcn_update_dpp(
        0, __float_as_int(x), 0x138, 0xf, 0xf, true));  // wave_shr:1, lane0->0
}
__device__ __forceinline__ int dpp_shr1_i32(int x) {
    return __builtin_amdgcn_update_dpp(0, x, 0x138, 0xf, 0xf, true);
}
__device__ __forceinline__ float wave_fsum_dpp(float x) {
    // canonical GCN full-wave sum; total lands in lane 63
    x += __int_as_float(__builtin_amdgcn_update_dpp(0, __float_as_int(x), 0x111, 0xf, 0xf, true));
    x += __int_as_float(__builtin_amdgcn_update_dpp(0, __float_as_int(x), 0x112, 0xf, 0xf, true));
    x += __int_as_float(__builtin_amdgcn_update_dpp(0, __float_as_int(x), 0x114, 0xf, 0xf, true));
    x += __int_as_float(__builtin_amdgcn_update_dpp(0, __float_as_int(x), 0x118, 0xf, 0xf, true));
    x += __int_as_float(__builtin_amdgcn_update_dpp(0, __float_as_int(x), 0x142, 0xa, 0xf, false));
    x += __int_as_float(__builtin_amdgcn_update_dpp(0, __float_as_int(x), 0x143, 0xc, 0xf, false));
    return x;
}

// Kernel 1: wave-per-row GEMV + softmax (coalesced; r11-proven).
__global__ __launch_bounds__(256) void k_logits_softmax(
    const float* __restrict__ hs, const float* __restrict__ W,
    const float* __restrict__ bias, float* __restrict__ logp,
    float* __restrict__ probs)
{
    const int lane = threadIdx.x & 63;
    const int wid  = (blockIdx.x * blockDim.x + threadIdx.x) >> 6;
    const int nwav = (gridDim.x * blockDim.x) >> 6;

    float wr[2][4][V_DIM];
#pragma unroll
    for (int c = 0; c < 2; ++c)
#pragma unroll
        for (int j = 0; j < 4; ++j) {
            const int k = c * 256 + lane * 4 + j;
#pragma unroll
            for (int v = 0; v < V_DIM; ++v) wr[c][j][v] = W[k * V_DIM + v];
        }
    float br[V_DIM];
#pragma unroll
    for (int v = 0; v < V_DIM; ++v) br[v] = bias[v];

    for (int row = wid; row < B_DIM * T_DIM; row += nwav) {
        const float* x = hs + (size_t)row * D_DIM;
        float4 xa = *reinterpret_cast<const float4*>(x + lane * 4);
        float4 xb = *reinterpret_cast<const float4*>(x + 256 + lane * 4);
        const float xs0[4] = {xa.x, xa.y, xa.z, xa.w};
        const float xs1[4] = {xb.x, xb.y, xb.z, xb.w};

        float acc[V_DIM];
#pragma unroll
        for (int v = 0; v < V_DIM; ++v) acc[v] = 0.f;
#pragma unroll
        for (int j = 0; j < 4; ++j)
#pragma unroll
            for (int v = 0; v < V_DIM; ++v) {
                acc[v] = fmaf(xs0[j], wr[0][j][v], acc[v]);
                acc[v] = fmaf(xs1[j], wr[1][j][v], acc[v]);
            }
#pragma unroll
        for (int v = 0; v < V_DIM; ++v) acc[v] = wave_fsum_dpp(acc[v]);

        if (lane == 63) {
#pragma unroll
            for (int v = 0; v < V_DIM; ++v) acc[v] += br[v];
            float m = fmaxf(fmaxf(fmaxf(acc[0], acc[1]), fmaxf(acc[2], acc[3])), acc[4]);
            float e[V_DIM], s = 0.f;
#pragma unroll
            for (int v = 0; v < V_DIM; ++v) { e[v] = __expf(acc[v] - m); s += e[v]; }
            float lse = m + __logf(s);
            float inv = 1.f / s;
            size_t base = (size_t)row * V_DIM;
#pragma unroll
            for (int v = 0; v < V_DIM; ++v) {
                logp[base + v]  = acc[v] - lse;
                probs[base + v] = e[v] * inv;
            }
        }
    }
}

// Kernel 2: CTC forward scan — blank-normalized f32 per-lane BFP, RENORM
// PERIOD 8 (r13/r14-proven). r15's period-16 experiment FAILED: injected
// boundary mass (<= p7 * 2^delta, delta clamp 52 -> ~2^53) times residual
// window growth (up to 2^100 over 16 steps) overflows f32 -> inf -> NaN
// cascade (~8 samples zeroed). At period 8: 2^17 * 2^50 = 2^67, safe by 60
// bits. Period 8 is structurally required; kept verbatim from r14.
// Retained r15 trims (semantically neutral, address/value-identical):
// (a) max3 tree for the 9-value renorm max (clang fuses to v_max3_f32);
// (b) pointer-advance group loads (running pointers +8/group, second b128
//     at imm offset:16 -> no per-group address recompute).
__global__ __launch_bounds__(64) void k_ctc(
    const float* __restrict__ probs, const int* __restrict__ ys_pad,
    const int* __restrict__ hlens, const int* __restrict__ ys_lens,
    float* __restrict__ nll_out)
{
    __shared__ float  s_probs[T_DIM * V_DIM];               // f32 staging
    __shared__ __align__(16) float s_pT[5][TP];             // rows 0..3: ratios; row 4: zeros
    __shared__ float  s_beta[513];
    __shared__ int    s_E[64];
    __shared__ double s_red[64];

    const int b    = blockIdx.x;
    const int lane = threadIdx.x;        // 0..63
    const int hlen = hlens[b];
    const int lb   = ys_lens[b];
    const int Sb   = 2 * lb + 1;
    const float* pb = probs + (size_t)b * T_DIM * V_DIM;
    const int*  yrow = ys_pad + b * L_DIM;

    // ---- stage all T*V probs into LDS (f32) ----
    for (int i = 0; i < (T_DIM * V_DIM) / 64; ++i) {
        __builtin_amdgcn_global_load_lds((gas_fp)(pb + i * 64 + lane),
                                         (las_fp)(&s_probs[i * 64]), 4, 0, 0);
    }
    asm volatile("s_waitcnt vmcnt(0)" ::: "memory");

    // ---- zero row (locks invalid odd states to 0) ----
    for (int i = lane; i < TP; i += 64) s_pT[4][i] = 0.f;

    // ---- transpose: blank-ratios r_t[y]=p_t[y]/p_t[blank] + sum log2(pb) ----
    double lg2 = 0.0;
    for (int i = 0; i < T_DIM / 64; ++i) {
        const int t = i * 64 + lane;
        const float* sp = &s_probs[t * 5];
        const float p0 = sp[0];
        const float inv = 1.0f / p0;
        s_pT[0][t + 3] = sp[1] * inv;
        s_pT[1][t + 3] = sp[2] * inv;
        s_pT[2][t + 3] = sp[3] * inv;
        s_pT[3][t + 3] = sp[4] * inv;
        if (t < hlen) {
            int ee; float mm = frexpf(p0, &ee);
            lg2 += (double)ee + (double)__log2f(mm);
        }
    }

    // labels for this lane's 4 odd states (8l+{1,3,5,7} -> labels 4l..4l+3)
    const int y0 = yrow[4 * lane + 0];
    const int y1 = yrow[4 * lane + 1];
    const int y2 = yrow[4 * lane + 2];
    const int y3 = yrow[4 * lane + 3];
    const int ym1 = (lane > 0) ? yrow[4 * lane - 1] : -1;

    const float sk0 = ((lane > 0) && (y0 != ym1)) ? 1.f : 0.f;
    const float sk1 = (y1 != y0) ? 1.f : 0.f;
    const float sk2 = (y2 != y1) ? 1.f : 0.f;
    const float sk3 = (y3 != y2) ? 1.f : 0.f;

    // ratio row pointers; invalid odd states -> zero row (locked to 0)
    const float* q_y0 = (8 * lane + 1 < Sb) ? &s_pT[y0 - 1][0] : &s_pT[4][0];
    const float* q_y1 = (8 * lane + 3 < Sb) ? &s_pT[y1 - 1][0] : &s_pT[4][0];
    const float* q_y2 = (8 * lane + 5 < Sb) ? &s_pT[y2 - 1][0] : &s_pT[4][0];
    const float* q_y3 = (8 * lane + 7 < Sb) ? &s_pT[y3 - 1][0] : &s_pT[4][0];

    float aA[9], aB[9];
#pragma unroll
    for (int i = 0; i < 9; ++i) aA[i] = 0.f;
    if (lane == 0) {
        aA[0] = 1.f;                     // beta_0[0]
        aA[1] = s_pT[y0 - 1][3];         // beta_0[1] = r_0[y0]
    }
    int E = 0;           // per-LANE frame exponent (true = rel * 2^E)
    float ds = 1.f;      // 2^delta (exact pow2), delta = E_prev - E
    float skd0 = sk0;    // sk0 * ds

    // running load pointers (advance +8 per 8-step group); t=1 at index 4
    const float* p_y0 = q_y0 + 4;
    const float* p_y1 = q_y1 + 4;
    const float* p_y2 = q_y2 + 4;
    const float* p_y3 = q_y3 + 4;

#define LD4F(d, p)                                                        \
    { float4 u_ = *(const float4*)(p);                                    \
      (d)[0] = u_.x; (d)[1] = u_.y; (d)[2] = u_.z; (d)[3] = u_.w; }

// 8-step group load from running pointers; second b128 at +4 floats
// (imm offset:16), then advance.
#define LOADO(dst)                                                        \
    { LD4F(dst + 0,  p_y0); LD4F(dst + 16, p_y0 + 4);                     \
      LD4F(dst + 4,  p_y1); LD4F(dst + 20, p_y1 + 4);                     \
      LD4F(dst + 8,  p_y2); LD4F(dst + 24, p_y2 + 4);                     \
      LD4F(dst + 12, p_y3); LD4F(dst + 28, p_y3 + 4);                     \
      p_y0 += 8; p_y1 += 8; p_y2 += 8; p_y3 += 8; }

// blank-normalized f32 step; frame delta pre-folded into ds / skd0.
#define STEPX(O, N, L, s_)                                                \
    {                                                                     \
        float p7_ = dpp_shr1_f32(O[7]);                                   \
        N[7] = fmaf(sk3, O[5], O[7] + O[6]) * L[12 + (s_)];               \
        N[2] = O[2] + O[1];                                               \
        N[3] = fmaf(sk1, O[1], O[3] + O[2]) * L[4 + (s_)];                \
        N[4] = O[4] + O[3];                                               \
        N[5] = fmaf(sk2, O[3], O[5] + O[4]) * L[8 + (s_)];                \
        N[6] = O[6] + O[5];                                               \
        N[8] = O[8] + O[7];                                               \
        N[0] = fmaf(p7_, ds, O[0]);                                       \
        N[1] = fmaf(skd0, p7_, O[1] + O[0]) * L[0 + (s_)];                \
    }

#define STEP8(L)                                                          \
    STEPX(aA, aB, L, 0);  STEPX(aB, aA, L, 1);                            \
    STEPX(aA, aB, L, 2);  STEPX(aB, aA, L, 3);                            \
    STEPX(aA, aB, L, 16); STEPX(aB, aA, L, 17);                           \
    STEPX(aA, aB, L, 18); STEPX(aB, aA, L, 19);

// Per-lane exact-pow2 renorm every 8 steps (max3 tree; no masks: invalid
// states are 0). Saturating scale (em<=253) + delta clamp [-126,52] keep
// inf/NaN unreachable at period 8 (r13/r14-proven: worst injected x growth
// = 2^17 * 2^50 = 2^67 << 2^127). Empty lanes adopt upstream E-16.
#define RENORM()                                                          \
    {                                                                     \
        const float x0_ = fmaxf(fmaxf(aA[0], aA[1]), aA[2]);              \
        const float x1_ = fmaxf(fmaxf(aA[3], aA[4]), aA[5]);              \
        const float x2_ = fmaxf(fmaxf(aA[6], aA[7]), aA[8]);              \
        const float m_  = fmaxf(fmaxf(x0_, x1_), x2_);                    \
        const bool big_ = (m_ >= 1e-12f);                                 \
        int em_ = (__float_as_int(m_) >> 23) & 0xff;                      \
        em_ = em_ > 253 ? 253 : em_;                                      \
        const float sc_ = __int_as_float((254 - (big_ ? em_ : 127)) << 23); \
        _Pragma("unroll")                                                 \
        for (int i_ = 0; i_ < 9; ++i_) aA[i_] *= sc_;                     \
        const int En_ = E + (big_ ? em_ - 127 : 0);                       \
        const int up_ = dpp_shr1_i32(En_);                                \
        E = (!big_ && lane > 0) ? (up_ - 16) : En_;                       \
        const int upE_ = dpp_shr1_i32(E);                                 \
        int d_ = upE_ - E;                                                \
        d_ = d_ > 52 ? 52 : d_;                                           \
        d_ = d_ < -126 ? -126 : d_;                                       \
        ds = __int_as_float((127 + d_) << 23);                            \
        skd0 = sk0 * ds;                                                  \
    }

    const int NS = hlen - 1;       // steps t = 1..NS
    const int ngrp = NS >> 3;      // full 8-step groups (>=127 since hlen>=1024)
    float lpA[32], lpB[32];
    LOADO(lpA);                    // group 0 (t=1..8)

    int g = 0;
    for (; g + 2 <= ngrp; g += 2) {
        LOADO(lpB);                // group g+1
        STEP8(lpA);
        RENORM();                  // every 8 steps (period 8: r14-proven)
        LOADO(lpA);                // group g+2
        STEP8(lpB);
        RENORM();
    }
    if (g < ngrp) {                // leftover full group, data in lpA
        STEP8(lpA);
        RENORM();
    }
    // tail steps (0..7): t = 8*ngrp+1 .. NS
    for (int tt = 8 * ngrp + 1; tt <= NS; ++tt) {
        float lt[16];
        lt[0]  = q_y0[tt + 3];
        lt[4]  = q_y1[tt + 3];
        lt[8]  = q_y2[tt + 3];
        lt[12] = q_y3[tt + 3];
        STEPX(aA, aB, lt, 0);
#pragma unroll
        for (int i = 0; i < 9; ++i) aA[i] = aB[i];
    }

    // ---- readout: merge per-lane frames in f64 ----
#pragma unroll
    for (int i = 0; i < 8; ++i) s_beta[8 * lane + i] = aA[i];
    if (lane == 63) s_beta[512] = aA[8];
    s_E[lane] = E;
    s_red[lane] = lg2;
    __syncthreads();
    if (lane == 0) {
        double lg2tot = 0.0;
        for (int i = 0; i < 64; ++i) lg2tot += s_red[i];
        const int i1 = 2 * lb - 1, i2 = 2 * lb;
        int l1 = i1 >> 3; if (l1 > 63) l1 = 63;
        int l2 = i2 >> 3; if (l2 > 63) l2 = 63;
        const int E1 = s_E[l1], E2 = s_E[l2];
        const int Em = (E1 > E2) ? E1 : E2;
        double s = ldexp((double)s_beta[i1], E1 - Em)
                 + ldexp((double)s_beta[i2], E2 - Em);
        double nlld = -(log(s) + ((double)Em + lg2tot) * LN2D);
        float nll = (float)nlld;
        if (!(fabsf(nll) < 1e8f)) nll = 0.f;   // zero_infinity (±inf / NaN)
        nll_out[b] = nll;
    }
#undef STEPX
#undef STEP8
#undef LOADO
#undef LD4F
#undef RENORM
}

// Kernel 3: deterministic reduction of 32 per-sample NLLs -> loss.
__global__ __launch_bounds__(64) void k_finalize(
    const float* __restrict__ nll, float* __restrict__ out)
{
    int tid = threadIdx.x;
    float v = (tid < B_DIM) ? nll[tid] : 0.f;
#pragma unroll
    for (int off = 32; off; off >>= 1) v += __shfl_down(v, off, 64);
    if (tid == 0) out[0] = v / (float)B_DIM;
}

extern "C" void kernel_launch(void* const* d_in, const int* in_sizes, int n_in,
                              void* d_out, int out_size, void* d_ws, size_t ws_size,
                              hipStream_t stream) {
    const float* hs      = (const float*)d_in[0];
    const float* W       = (const float*)d_in[1];
    const float* bias    = (const float*)d_in[2];
    const int*   hlens   = (const int*)d_in[3];
    const int*   ys_pad  = (const int*)d_in[4];
    const int*   ys_lens = (const int*)d_in[5];

    float* out   = (float*)d_out;
    float* logp  = out + 1;                                      // (B,T,V) log-softmax
    float* probs = out + 1 + (size_t)B_DIM * T_DIM * V_DIM;      // (B,T,V) softmax
    float* nll   = (float*)d_ws;                                 // 32 floats

    hipLaunchKernelGGL(k_logits_softmax, dim3(1024), dim3(256), 0, stream,
                       hs, W, bias, logp, probs);
    hipLaunchKernelGGL(k_ctc, dim3(B_DIM), dim3(64), 0, stream,
                       probs, ys_pad, hlens, ys_lens, nll);
    hipLaunchKernelGGL(k_finalize, dim3(1), dim3(64), 0, stream, nll, out);
}

// Round 17
// 127.287 us; speedup vs baseline: 1.0216x; 1.0216x over previous
//
#include <hip/hip_runtime.h>
#include <math.h>

#define B_DIM 32
#define T_DIM 2048
#define D_DIM 512
#define V_DIM 5
#define L_DIM 256
#define LN2D 0.6931471805599453
#define TP (T_DIM + 4)

typedef const float __attribute__((address_space(1)))* gas_fp;
typedef float __attribute__((address_space(3)))* las_fp;

// ---- DPP helpers (VALU cross-lane, no DS pipe) ----
__device__ __forceinline__ float dpp_shr1_f32(float x) {
    return __int_as_float(__builtin_amdgcn_update_dpp(
        0, __float_as_int(x), 0x138, 0xf, 0xf, true));  // wave_shr:1, lane0->0
}
__device__ __forceinline__ int dpp_shr1_i32(int x) {
    return __builtin_amdgcn_update_dpp(0, x, 0x138, 0xf, 0xf, true);
}
__device__ __forceinline__ float wave_fsum_dpp(float x) {
    // canonical GCN full-wave sum; total lands in lane 63
    x += __int_as_float(__builtin_amdgcn_update_dpp(0, __float_as_int(x), 0x111, 0xf, 0xf, true));
    x += __int_as_float(__builtin_amdgcn_update_dpp(0, __float_as_int(x), 0x112, 0xf, 0xf, true));
    x += __int_as_float(__builtin_amdgcn_update_dpp(0, __float_as_int(x), 0x114, 0xf, 0xf, true));
    x += __int_as_float(__builtin_amdgcn_update_dpp(0, __float_as_int(x), 0x118, 0xf, 0xf, true));
    x += __int_as_float(__builtin_amdgcn_update_dpp(0, __float_as_int(x), 0x142, 0xa, 0xf, false));
    x += __int_as_float(__builtin_amdgcn_update_dpp(0, __float_as_int(x), 0x143, 0xc, 0xf, false));
    return x;
}

// Kernel 1: wave-per-row GEMV + softmax (coalesced; r11-proven).
__global__ __launch_bounds__(256) void k_logits_softmax(
    const float* __restrict__ hs, const float* __restrict__ W,
    const float* __restrict__ bias, float* __restrict__ logp,
    float* __restrict__ probs)
{
    const int lane = threadIdx.x & 63;
    const int wid  = (blockIdx.x * blockDim.x + threadIdx.x) >> 6;
    const int nwav = (gridDim.x * blockDim.x) >> 6;

    float wr[2][4][V_DIM];
#pragma unroll
    for (int c = 0; c < 2; ++c)
#pragma unroll
        for (int j = 0; j < 4; ++j) {
            const int k = c * 256 + lane * 4 + j;
#pragma unroll
            for (int v = 0; v < V_DIM; ++v) wr[c][j][v] = W[k * V_DIM + v];
        }
    float br[V_DIM];
#pragma unroll
    for (int v = 0; v < V_DIM; ++v) br[v] = bias[v];

    for (int row = wid; row < B_DIM * T_DIM; row += nwav) {
        const float* x = hs + (size_t)row * D_DIM;
        float4 xa = *reinterpret_cast<const float4*>(x + lane * 4);
        float4 xb = *reinterpret_cast<const float4*>(x + 256 + lane * 4);
        const float xs0[4] = {xa.x, xa.y, xa.z, xa.w};
        const float xs1[4] = {xb.x, xb.y, xb.z, xb.w};

        float acc[V_DIM];
#pragma unroll
        for (int v = 0; v < V_DIM; ++v) acc[v] = 0.f;
#pragma unroll
        for (int j = 0; j < 4; ++j)
#pragma unroll
            for (int v = 0; v < V_DIM; ++v) {
                acc[v] = fmaf(xs0[j], wr[0][j][v], acc[v]);
                acc[v] = fmaf(xs1[j], wr[1][j][v], acc[v]);
            }
#pragma unroll
        for (int v = 0; v < V_DIM; ++v) acc[v] = wave_fsum_dpp(acc[v]);

        if (lane == 63) {
#pragma unroll
            for (int v = 0; v < V_DIM; ++v) acc[v] += br[v];
            float m = fmaxf(fmaxf(fmaxf(acc[0], acc[1]), fmaxf(acc[2], acc[3])), acc[4]);
            float e[V_DIM], s = 0.f;
#pragma unroll
            for (int v = 0; v < V_DIM; ++v) { e[v] = __expf(acc[v] - m); s += e[v]; }
            float lse = m + __logf(s);
            float inv = 1.f / s;
            size_t base = (size_t)row * V_DIM;
#pragma unroll
            for (int v = 0; v < V_DIM; ++v) {
                logp[base + v]  = acc[v] - lse;
                probs[base + v] = e[v] * inv;
            }
        }
    }
}

// Kernel 2: CTC forward scan — blank-normalized f32 per-lane BFP (r13/r14-
// proven numerics, RENORM PERIOD 8). This is the r14 champion verbatim
// (114 µs k_ctc / 127.5 µs total, absmax 0.0078125). r15/r16 established:
// (i) period 16 overflows (injected mass x window growth > 2^127 -> NaN);
// (ii) max3/pointer-advance trims are neutral-to-negative — the kernel sits
// at its dependent-chain/issue floor, where removed instructions were
// hidden under the recurrence's latency anyway.
__global__ __launch_bounds__(64) void k_ctc(
    const float* __restrict__ probs, const int* __restrict__ ys_pad,
    const int* __restrict__ hlens, const int* __restrict__ ys_lens,
    float* __restrict__ nll_out)
{
    __shared__ float  s_probs[T_DIM * V_DIM];               // f32 staging
    __shared__ __align__(16) float s_pT[5][TP];             // rows 0..3: ratios; row 4: zeros
    __shared__ float  s_beta[513];
    __shared__ int    s_E[64];
    __shared__ double s_red[64];

    const int b    = blockIdx.x;
    const int lane = threadIdx.x;        // 0..63
    const int hlen = hlens[b];
    const int lb   = ys_lens[b];
    const int Sb   = 2 * lb + 1;
    const float* pb = probs + (size_t)b * T_DIM * V_DIM;
    const int*  yrow = ys_pad + b * L_DIM;

    // ---- stage all T*V probs into LDS (f32) ----
    for (int i = 0; i < (T_DIM * V_DIM) / 64; ++i) {
        __builtin_amdgcn_global_load_lds((gas_fp)(pb + i * 64 + lane),
                                         (las_fp)(&s_probs[i * 64]), 4, 0, 0);
    }
    asm volatile("s_waitcnt vmcnt(0)" ::: "memory");

    // ---- zero row (locks invalid odd states to 0) ----
    for (int i = lane; i < TP; i += 64) s_pT[4][i] = 0.f;

    // ---- transpose: blank-ratios r_t[y]=p_t[y]/p_t[blank] + sum log2(pb) ----
    double lg2 = 0.0;
    for (int i = 0; i < T_DIM / 64; ++i) {
        const int t = i * 64 + lane;
        const float* sp = &s_probs[t * 5];
        const float p0 = sp[0];
        const float inv = 1.0f / p0;
        s_pT[0][t + 3] = sp[1] * inv;
        s_pT[1][t + 3] = sp[2] * inv;
        s_pT[2][t + 3] = sp[3] * inv;
        s_pT[3][t + 3] = sp[4] * inv;
        if (t < hlen) {
            int ee; float mm = frexpf(p0, &ee);
            lg2 += (double)ee + (double)__log2f(mm);
        }
    }

    // labels for this lane's 4 odd states (8l+{1,3,5,7} -> labels 4l..4l+3)
    const int y0 = yrow[4 * lane + 0];
    const int y1 = yrow[4 * lane + 1];
    const int y2 = yrow[4 * lane + 2];
    const int y3 = yrow[4 * lane + 3];
    const int ym1 = (lane > 0) ? yrow[4 * lane - 1] : -1;

    const float sk0 = ((lane > 0) && (y0 != ym1)) ? 1.f : 0.f;
    const float sk1 = (y1 != y0) ? 1.f : 0.f;
    const float sk2 = (y2 != y1) ? 1.f : 0.f;
    const float sk3 = (y3 != y2) ? 1.f : 0.f;

    // ratio row pointers; invalid odd states -> zero row (locked to 0)
    const float* q_y0 = (8 * lane + 1 < Sb) ? &s_pT[y0 - 1][0] : &s_pT[4][0];
    const float* q_y1 = (8 * lane + 3 < Sb) ? &s_pT[y1 - 1][0] : &s_pT[4][0];
    const float* q_y2 = (8 * lane + 5 < Sb) ? &s_pT[y2 - 1][0] : &s_pT[4][0];
    const float* q_y3 = (8 * lane + 7 < Sb) ? &s_pT[y3 - 1][0] : &s_pT[4][0];

    float aA[9], aB[9];
#pragma unroll
    for (int i = 0; i < 9; ++i) aA[i] = 0.f;
    if (lane == 0) {
        aA[0] = 1.f;                     // beta_0[0]
        aA[1] = s_pT[y0 - 1][3];         // beta_0[1] = r_0[y0]
    }
    int E = 0;           // per-LANE frame exponent (true = rel * 2^E)
    float ds = 1.f;      // 2^delta (exact pow2), delta = E_prev - E
    float skd0 = sk0;    // sk0 * ds

#define LD4F(d, p)                                                        \
    { float4 u_ = *(const float4*)(p);                                    \
      (d)[0] = u_.x; (d)[1] = u_.y; (d)[2] = u_.z; (d)[3] = u_.w; }

// 8-step group load: rows stride-4, two 4-step sub-blocks at +0 / +16
#define LOADO(dst, gg)                                                    \
    { const int off_ = 4 + 8 * (gg);                                      \
      LD4F(dst + 0,  q_y0 + off_); LD4F(dst + 16, q_y0 + off_ + 4);       \
      LD4F(dst + 4,  q_y1 + off_); LD4F(dst + 20, q_y1 + off_ + 4);       \
      LD4F(dst + 8,  q_y2 + off_); LD4F(dst + 24, q_y2 + off_ + 4);       \
      LD4F(dst + 12, q_y3 + off_); LD4F(dst + 28, q_y3 + off_ + 4); }

// blank-normalized f32 step; frame delta pre-folded into ds / skd0.
#define STEPX(O, N, L, s_)                                                \
    {                                                                     \
        float p7_ = dpp_shr1_f32(O[7]);                                   \
        N[7] = fmaf(sk3, O[5], O[7] + O[6]) * L[12 + (s_)];               \
        N[2] = O[2] + O[1];                                               \
        N[3] = fmaf(sk1, O[1], O[3] + O[2]) * L[4 + (s_)];                \
        N[4] = O[4] + O[3];                                               \
        N[5] = fmaf(sk2, O[3], O[5] + O[4]) * L[8 + (s_)];                \
        N[6] = O[6] + O[5];                                               \
        N[8] = O[8] + O[7];                                               \
        N[0] = fmaf(p7_, ds, O[0]);                                       \
        N[1] = fmaf(skd0, p7_, O[1] + O[0]) * L[0 + (s_)];                \
    }

#define STEP8(L)                                                          \
    STEPX(aA, aB, L, 0);  STEPX(aB, aA, L, 1);                            \
    STEPX(aA, aB, L, 2);  STEPX(aB, aA, L, 3);                            \
    STEPX(aA, aB, L, 16); STEPX(aB, aA, L, 17);                           \
    STEPX(aA, aB, L, 18); STEPX(aB, aA, L, 19);

// Per-lane exact-pow2 renorm every 8 steps (no masks: invalid states are 0).
// Saturating scale (em<=253) and delta clamp [-126,52] keep inf/NaN
// unreachable (r13-proven). Empty lanes (max==0) adopt upstream E-16.
#define RENORM()                                                          \
    {                                                                     \
        float m_ = aA[0];                                                 \
        _Pragma("unroll")                                                 \
        for (int i_ = 1; i_ < 9; ++i_) m_ = fmaxf(m_, aA[i_]);            \
        const bool big_ = (m_ >= 1e-12f);                                 \
        int em_ = (__float_as_int(m_) >> 23) & 0xff;                      \
        em_ = em_ > 253 ? 253 : em_;                                      \
        const float sc_ = __int_as_float((254 - (big_ ? em_ : 127)) << 23); \
        _Pragma("unroll")                                                 \
        for (int i_ = 0; i_ < 9; ++i_) aA[i_] *= sc_;                     \
        const int En_ = E + (big_ ? em_ - 127 : 0);                       \
        const int up_ = dpp_shr1_i32(En_);                                \
        E = (!big_ && lane > 0) ? (up_ - 16) : En_;                       \
        const int upE_ = dpp_shr1_i32(E);                                 \
        int d_ = upE_ - E;                                                \
        d_ = d_ > 52 ? 52 : d_;                                           \
        d_ = d_ < -126 ? -126 : d_;                                       \
        ds = __int_as_float((127 + d_) << 23);                            \
        skd0 = sk0 * ds;                                                  \
    }

    const int NS = hlen - 1;       // steps t = 1..NS
    const int ngrp = NS >> 3;      // full 8-step groups (>=127 since hlen>=1024)
    float lpA[32], lpB[32];
    LOADO(lpA, 0);                 // group 0 (t=1..8)

    int g = 0;
    for (; g + 2 <= ngrp; g += 2) {
        LOADO(lpB, g + 1);
        STEP8(lpA);
        RENORM();
        LOADO(lpA, g + 2);
        STEP8(lpB);
        RENORM();
    }
    if (g < ngrp) {                // leftover full group, data in lpA
        STEP8(lpA);
        RENORM();
    }
    // tail steps (0..7): t = 8*ngrp+1 .. NS
    for (int tt = 8 * ngrp + 1; tt <= NS; ++tt) {
        float lt[16];
        lt[0]  = q_y0[tt + 3];
        lt[4]  = q_y1[tt + 3];
        lt[8]  = q_y2[tt + 3];
        lt[12] = q_y3[tt + 3];
        STEPX(aA, aB, lt, 0);
#pragma unroll
        for (int i = 0; i < 9; ++i) aA[i] = aB[i];
    }

    // ---- readout: merge per-lane frames in f64 ----
#pragma unroll
    for (int i = 0; i < 8; ++i) s_beta[8 * lane + i] = aA[i];
    if (lane == 63) s_beta[512] = aA[8];
    s_E[lane] = E;
    s_red[lane] = lg2;
    __syncthreads();
    if (lane == 0) {
        double lg2tot = 0.0;
        for (int i = 0; i < 64; ++i) lg2tot += s_red[i];
        const int i1 = 2 * lb - 1, i2 = 2 * lb;
        int l1 = i1 >> 3; if (l1 > 63) l1 = 63;
        int l2 = i2 >> 3; if (l2 > 63) l2 = 63;
        const int E1 = s_E[l1], E2 = s_E[l2];
        const int Em = (E1 > E2) ? E1 : E2;
        double s = ldexp((double)s_beta[i1], E1 - Em)
                 + ldexp((double)s_beta[i2], E2 - Em);
        double nlld = -(log(s) + ((double)Em + lg2tot) * LN2D);
        float nll = (float)nlld;
        if (!(fabsf(nll) < 1e8f)) nll = 0.f;   // zero_infinity (±inf / NaN)
        nll_out[b] = nll;
    }
#undef STEPX
#undef STEP8
#undef LOADO
#undef LD4F
#undef RENORM
}

// Kernel 3: deterministic reduction of 32 per-sample NLLs -> loss.
__global__ __launch_bounds__(64) void k_finalize(
    const float* __restrict__ nll, float* __restrict__ out)
{
    int tid = threadIdx.x;
    float v = (tid < B_DIM) ? nll[tid] : 0.f;
#pragma unroll
    for (int off = 32; off; off >>= 1) v += __shfl_down(v, off, 64);
    if (tid == 0) out[0] = v / (float)B_DIM;
}

extern "C" void kernel_launch(void* const* d_in, const int* in_sizes, int n_in,
                              void* d_out, int out_size, void* d_ws, size_t ws_size,
                              hipStream_t stream) {
    const float* hs      = (const float*)d_in[0];
    const float* W       = (const float*)d_in[1];
    const float* bias    = (const float*)d_in[2];
    const int*   hlens   = (const int*)d_in[3];
    const int*   ys_pad  = (const int*)d_in[4];
    const int*   ys_lens = (const int*)d_in[5];

    float* out   = (float*)d_out;
    float* logp  = out + 1;                                      // (B,T,V) log-softmax
    float* probs = out + 1 + (size_t)B_DIM * T_DIM * V_DIM;      // (B,T,V) softmax
    float* nll   = (float*)d_ws;                                 // 32 floats

    hipLaunchKernelGGL(k_logits_softmax, dim3(1024), dim3(256), 0, stream,
                       hs, W, bias, logp, probs);
    hipLaunchKernelGGL(k_ctc, dim3(B_DIM), dim3(64), 0, stream,
                       probs, ys_pad, hlens, ys_lens, nll);
    hipLaunchKernelGGL(k_finalize, dim3(1), dim3(64), 0, stream, nll, out);
}